// Round 4
// baseline (42072.623 us; speedup 1.0000x reference)
//
#include <hip/hip_runtime.h>
#include <cstdint>

#define B_    64
#define T_    4096
#define F_    100
#define H_    200
#define G_    600
#define GP_   208          // padded gate width (13 tiles of 16)
#define NP_   624          // 3 * GP_
#define HSTR_ 232          // hA row stride in halves (pad past 224)
#define NWHB_ (7*39*4*16*8)  // whB elements: [kt][tile][quad][n][j]

typedef _Float16 half8 __attribute__((ext_vector_type(8)));
typedef float    f32x4 __attribute__((ext_vector_type(4)));

__device__ __forceinline__ float sig_(float x){ return 1.f/(1.f+__expf(-x)); }
__device__ __forceinline__ float tanh_(float x){ float e=__expf(-2.f*x); return (1.f-e)/(1.f+e); }

// ---- pack Wh [200][600] f32 -> B-fragment layout f16 ----
// whB[(((kt*39+tile)*4+quad)*16+n)*8+j] = Wh[k=kt*32+quad*8+j][col], zero-padded
// tile t: gate g=t/13, unit u=(t%13)*16+n; real col = g*200+u (valid u<200,k<200)
__global__ void prep_whB(const float* __restrict__ Wh, _Float16* __restrict__ whB) {
    int i = blockIdx.x * 256 + threadIdx.x;
    if (i >= NWHB_) return;
    int j = i & 7, n = (i >> 3) & 15, q = (i >> 7) & 3, rest = i >> 9;
    int tile = rest % 39, kt = rest / 39;
    int k = kt * 32 + q * 8 + j;
    int g = tile / 13, u = (tile % 13) * 16 + n;
    float v = 0.f;
    if (k < H_ && u < H_) v = Wh[k * G_ + g * H_ + u];
    whB[i] = (_Float16)v;
}

// ---- unified worker: blocks [0,scanN)=scan, [scanN,scanN+giN)=gi, rest=outproj ----
__global__ __launch_bounds__(512, 2)
void work_kernel(int scanN, int giN, int outN,
                 const float* __restrict__ x, const float* __restrict__ Wi,
                 const float* __restrict__ bi, const _Float16* __restrict__ whB,
                 const float* __restrict__ bhn, const float* __restrict__ Wo,
                 const float* __restrict__ bo,
                 float* gi0, float* gi1, _Float16* hs0, _Float16* hs1,
                 _Float16* hstate, float* __restrict__ out,
                 int TC, int scanC, int giC, int outC)
{
    __shared__ __align__(16) char smem[27232];
    const int bid = blockIdx.x, tid = threadIdx.x;

    if (bid < scanN) {
        // ================= GRU scan: 16 batches/block via MFMA =================
        _Float16* hA = (_Float16*)smem;                 // [16][HSTR_] f16
        const float* giBuf = (scanC & 1) ? gi1 : gi0;
        _Float16*    hsBuf = (scanC & 1) ? hs1 : hs0;
        const int first = (scanC == 0);
        const int b0 = bid * 16;
        const int w = tid >> 6, l = tid & 63, quad = l >> 4, n16 = l & 15;
        const int ntr = (w < 5) ? 2 : 1;                // triples: w<5:{2w,2w+1}, else {5+w}
        const int tr0 = (w < 5) ? 2 * w : (5 + w);
        const int u0 = tr0 * 16 + n16, u1 = u0 + 16;

        half8 Bf[42];
        #pragma unroll
        for (int i = 0; i < 42; ++i)
            #pragma unroll
            for (int j = 0; j < 8; ++j) Bf[i][j] = (_Float16)0.f;
        for (int tr2 = 0; tr2 < ntr; ++tr2) {
            int tr = tr0 + tr2;
            #pragma unroll
            for (int g = 0; g < 3; ++g) {
                int tile = g * 13 + tr;
                #pragma unroll
                for (int kt = 0; kt < 7; ++kt)
                    Bf[(tr2*3+g)*7+kt] =
                        *(const half8*)(whB + (size_t)(((kt*39 + tile)*4 + quad)*16 + n16)*8);
            }
        }
        float bh0 = (u0 < H_) ? bhn[u0] : 0.f;
        float bh1 = (ntr > 1 && u1 < H_) ? bhn[u1] : 0.f;

        for (int i = tid; i < 16 * HSTR_; i += 512) hA[i] = (_Float16)0.f;
        __syncthreads();
        if (!first) {
            for (int i = tid; i < 16 * H_; i += 512) {
                int m = i / H_, uu = i - m * H_;
                hA[m * HSTR_ + uu] = hstate[(b0 + m) * H_ + uu];
            }
        }
        __syncthreads();
        float ho[8];
        #pragma unroll
        for (int r = 0; r < 4; ++r) {
            ho[r]     = (float)hA[(quad*4+r)*HSTR_ + u0];
            ho[4 + r] = (ntr > 1) ? (float)hA[(quad*4+r)*HSTR_ + u1] : 0.f;
        }
        const float* gp = giBuf + (size_t)(b0 + quad*4) * TC * NP_;
        const size_t rstr = (size_t)TC * NP_;
        _Float16* hp = hsBuf + (size_t)(b0 + quad*4) * TC * GP_;
        const size_t hrstr = (size_t)TC * GP_;

        for (int t = 0; t < TC; ++t) {
            float gv[24];
            #pragma unroll
            for (int tr2 = 0; tr2 < 2; ++tr2) {
                if (tr2 < ntr) {
                    int ub = tr2 ? u1 : u0;
                    #pragma unroll
                    for (int g = 0; g < 3; ++g)
                        #pragma unroll
                        for (int r = 0; r < 4; ++r)
                            gv[(tr2*3+g)*4+r] = gp[(size_t)r * rstr + g * GP_ + ub];
                }
            }
            f32x4 acc[6];
            #pragma unroll
            for (int i = 0; i < 6; ++i) acc[i] = (f32x4){0.f, 0.f, 0.f, 0.f};
            #pragma unroll
            for (int kt = 0; kt < 7; ++kt) {
                half8 a = *(const half8*)&hA[n16 * HSTR_ + kt * 32 + quad * 8];
                acc[0] = __builtin_amdgcn_mfma_f32_16x16x32_f16(a, Bf[kt],      acc[0], 0, 0, 0);
                acc[1] = __builtin_amdgcn_mfma_f32_16x16x32_f16(a, Bf[7 + kt],  acc[1], 0, 0, 0);
                acc[2] = __builtin_amdgcn_mfma_f32_16x16x32_f16(a, Bf[14 + kt], acc[2], 0, 0, 0);
                if (ntr > 1) {
                    acc[3] = __builtin_amdgcn_mfma_f32_16x16x32_f16(a, Bf[21 + kt], acc[3], 0, 0, 0);
                    acc[4] = __builtin_amdgcn_mfma_f32_16x16x32_f16(a, Bf[28 + kt], acc[4], 0, 0, 0);
                    acc[5] = __builtin_amdgcn_mfma_f32_16x16x32_f16(a, Bf[35 + kt], acc[5], 0, 0, 0);
                }
            }
            __syncthreads();   // all hA reads done before rewrite
            #pragma unroll
            for (int tr2 = 0; tr2 < 2; ++tr2) {
                if (tr2 < ntr) {
                    int ub = tr2 ? u1 : u0;
                    float bh = tr2 ? bh1 : bh0;
                    #pragma unroll
                    for (int r = 0; r < 4; ++r) {
                        float rr = sig_(gv[(tr2*3+0)*4+r] + acc[tr2*3+0][r]);
                        float zz = sig_(gv[(tr2*3+1)*4+r] + acc[tr2*3+1][r]);
                        float nn = tanh_(gv[(tr2*3+2)*4+r] + rr * (acc[tr2*3+2][r] + bh));
                        float hv = ho[tr2*4+r];
                        hv = nn + zz * (hv - nn);
                        ho[tr2*4+r] = hv;
                        _Float16 hf = (_Float16)hv;
                        hA[(quad*4+r)*HSTR_ + ub] = hf;
                        hp[(size_t)r * hrstr + ub] = hf;
                    }
                }
            }
            __syncthreads();   // writes visible before next step's reads
            gp += NP_; hp += GP_;
        }
        #pragma unroll
        for (int tr2 = 0; tr2 < 2; ++tr2) {
            if (tr2 < ntr) {
                int ub = tr2 ? u1 : u0;
                if (ub < H_)
                    #pragma unroll
                    for (int r = 0; r < 4; ++r)
                        hstate[(size_t)(b0 + quad*4 + r) * H_ + ub] = (_Float16)ho[tr2*4+r];
            }
        }
    } else if (bid < scanN + giN) {
        // ================= gi = x @ Wi + bi (padded [b][t][624]) =================
        float* giBuf = (giC & 1) ? gi1 : gi0;
        float* xT = (float*)smem;                        // [100][68]
        int gib = bid - scanN;
        int row0 = gib * 64;                             // chunk-row (b*TC + t), 64 aligned
        int b = row0 / TC, tl0 = row0 - b * TC;
        const float* xr = x + ((size_t)b * T_ + (size_t)giC * TC + tl0) * F_;
        for (int i = tid; i < 64 * F_; i += 512) {
            int r = i / F_, f = i - r * F_;
            xT[f * 68 + r] = xr[i];
        }
        __syncthreads();
        for (int pass = 0; pass < 2; ++pass) {
            int p = pass * 512 + tid;
            if (p < NP_) {
                int g = p / GP_, u = p - g * GP_;
                bool valid = (u < H_);
                float acc[64];
                #pragma unroll
                for (int r = 0; r < 64; ++r) acc[r] = 0.f;
                if (valid) {
                    int wcol = g * H_ + u;
                    for (int f = 0; f < F_; ++f) {
                        float wv = Wi[f * G_ + wcol];
                        const float4* xf = (const float4*)&xT[f * 68];
                        #pragma unroll
                        for (int q = 0; q < 16; ++q) {
                            float4 v = xf[q];
                            acc[4*q+0] = fmaf(v.x, wv, acc[4*q+0]);
                            acc[4*q+1] = fmaf(v.y, wv, acc[4*q+1]);
                            acc[4*q+2] = fmaf(v.z, wv, acc[4*q+2]);
                            acc[4*q+3] = fmaf(v.w, wv, acc[4*q+3]);
                        }
                    }
                }
                float bv = valid ? bi[g * H_ + u] : 0.f;
                float* grow = giBuf + (size_t)row0 * NP_ + p;
                for (int r = 0; r < 64; ++r)
                    grow[(size_t)r * NP_] = valid ? (acc[r] + bv) : 0.f;
            }
        }
    } else {
        // ================= outproj: out = hs @ Wo + bo =================
        const _Float16* hsBuf = (outC & 1) ? hs1 : hs0;
        float* Wos = (float*)smem;
        if (tid < H_) Wos[tid] = Wo[tid];
        __syncthreads();
        int row = (bid - scanN - giN) * 512 + tid;
        if (row < B_ * TC) {
            const float4* hp4 = (const float4*)(hsBuf + (size_t)row * GP_);
            float acc = 0.f;
            #pragma unroll
            for (int q = 0; q < 25; ++q) {
                float4 v = hp4[q];
                const _Float16* hh = (const _Float16*)&v;
                #pragma unroll
                for (int j = 0; j < 8; ++j) acc = fmaf((float)hh[j], Wos[q*8+j], acc);
            }
            int b = row / TC, t = row - b * TC;
            out[(size_t)b * T_ + (size_t)outC * TC + t] = acc + bo[0];
        }
    }
}

extern "C" void kernel_launch(void* const* d_in, const int* in_sizes, int n_in,
                              void* d_out, int out_size, void* d_ws, size_t ws_size,
                              hipStream_t stream) {
    const float* x   = (const float*)d_in[0];
    const float* Wi  = (const float*)d_in[1];
    const float* bi  = (const float*)d_in[2];
    const float* Wh  = (const float*)d_in[3];
    const float* bhn = (const float*)d_in[4];
    const float* Wo  = (const float*)d_in[5];
    const float* bo  = (const float*)d_in[6];
    float* out = (float*)d_out;

    const size_t fixed = (size_t)NWHB_ * 2 + (size_t)B_ * H_ * 2 + 1024;
    int TC = 2048;
    while (TC > 64) {
        size_t need = 2 * ((size_t)B_ * TC * NP_ * 4) + 2 * ((size_t)B_ * TC * GP_ * 2) + fixed;
        if (need <= ws_size) break;
        TC >>= 1;
    }
    char* pp = (char*)d_ws;
    float*    gi0 = (float*)pp;     pp += (size_t)B_ * TC * NP_ * 4;
    float*    gi1 = (float*)pp;     pp += (size_t)B_ * TC * NP_ * 4;
    _Float16* hs0 = (_Float16*)pp;  pp += (size_t)B_ * TC * GP_ * 2;
    _Float16* hs1 = (_Float16*)pp;  pp += (size_t)B_ * TC * GP_ * 2;
    _Float16* whB = (_Float16*)pp;  pp += (size_t)NWHB_ * 2;
    _Float16* hstate = (_Float16*)pp;

    const int nch = T_ / TC;
    const int giN = B_ * TC / 64, outN = B_ * TC / 512;

    prep_whB<<<dim3((NWHB_ + 255) / 256), dim3(256), 0, stream>>>(Wh, whB);
    // prologue: gi chunk 0
    work_kernel<<<dim3(giN), dim3(512), 0, stream>>>(0, giN, 0,
        x, Wi, bi, whB, bhn, Wo, bo, gi0, gi1, hs0, hs1, hstate, out,
        TC, 0, 0, 0);
    for (int c = 0; c < nch; ++c) {
        int gC = (c + 1 < nch) ? c + 1 : -1;
        int oC = (c > 0) ? c - 1 : -1;
        int gn = (gC >= 0) ? giN : 0, on = (oC >= 0) ? outN : 0;
        work_kernel<<<dim3(4 + gn + on), dim3(512), 0, stream>>>(4, gn, on,
            x, Wi, bi, whB, bhn, Wo, bo, gi0, gi1, hs0, hs1, hstate, out,
            TC, c, gC, oC);
    }
    // epilogue: outproj of last chunk
    work_kernel<<<dim3(outN), dim3(512), 0, stream>>>(0, 0, outN,
        x, Wi, bi, whB, bhn, Wo, bo, gi0, gi1, hs0, hs1, hstate, out,
        TC, 0, 0, nch - 1);
}

// Round 5
// 37543.375 us; speedup vs baseline: 1.1206x; 1.1206x over previous
//
#include <hip/hip_runtime.h>
#include <cstdint>

#define B_    64
#define T_    4096
#define F_    100
#define H_    200
#define G_    600
#define GP_   208           // padded gate width (13 tiles of 16)
#define NP_   624           // 3 * GP_
#define HSTR_ 232           // hA row stride in halves
#define NWHB_ (7*39*4*16*8) // whB: [kt][tile][quad][n][j]

typedef _Float16 half8 __attribute__((ext_vector_type(8)));
typedef _Float16 half4 __attribute__((ext_vector_type(4)));
typedef float    f32x4 __attribute__((ext_vector_type(4)));

__device__ __forceinline__ float sig_(float x){ return 1.f/(1.f+__expf(-x)); }
__device__ __forceinline__ float tanh_(float x){ float e=__expf(-2.f*x); return (1.f-e)/(1.f+e); }

// ---- pack Wh [200][600] f32 -> B-fragment layout f16 (validated in R4) ----
__global__ void prep_whB(const float* __restrict__ Wh, _Float16* __restrict__ whB) {
    int i = blockIdx.x * 256 + threadIdx.x;
    if (i >= NWHB_) return;
    int j = i & 7, n = (i >> 3) & 15, q = (i >> 7) & 3, rest = i >> 9;
    int tile = rest % 39, kt = rest / 39;
    int k = kt * 32 + q * 8 + j;
    int g = tile / 13, u = (tile % 13) * 16 + n;
    float v = 0.f;
    if (k < H_ && u < H_) v = Wh[k * G_ + g * H_ + u];
    whB[i] = (_Float16)v;
}

// gi layout: [bgrp(16)][t(TC)][col(NP_)][4 batches] f32
// hs layout: [bgrp(16)][t(TC)][u(GP_)][4 batches] f16
__global__ __launch_bounds__(512, 2)
void work_kernel(int scanN, int giN, int outN,
                 const float* __restrict__ x, const float* __restrict__ Wi,
                 const float* __restrict__ bi, const _Float16* __restrict__ whB,
                 const float* __restrict__ bhn, const float* __restrict__ Wo,
                 const float* __restrict__ bo,
                 float* gi0, float* gi1, _Float16* hs0, _Float16* hs1,
                 _Float16* hstate, float* __restrict__ out,
                 int TC, int scanC, int giC, int outC)
{
    __shared__ __align__(16) char smem[14464];
    const int bid = blockIdx.x, tid = threadIdx.x;

    if (bid < scanN) {
        // ============ GRU scan: 16 batches/block, MFMA, gi as C operand ============
        _Float16* hA = (_Float16*)smem;               // [16][HSTR_] f16
        const float* giBuf = (scanC & 1) ? gi1 : gi0;
        _Float16*    hsBuf = (scanC & 1) ? hs1 : hs0;
        const int first = (scanC == 0);
        const int b0 = bid * 16;
        const int w = tid >> 6, l = tid & 63, quad = l >> 4, n16 = l & 15;
        const int ntr = (w < 5) ? 2 : 1;              // waves 0-4: 2 triples, 5-7: 1
        const int tr0 = (w < 5) ? 2 * w : (5 + w);    // w5->10 w6->11 w7->12
        const int u0 = tr0 * 16 + n16, u1 = u0 + 16;

        half8 Bf[42];
        #pragma unroll
        for (int i = 0; i < 42; ++i)
            #pragma unroll
            for (int j = 0; j < 8; ++j) Bf[i][j] = (_Float16)0.f;
        for (int tr2 = 0; tr2 < ntr; ++tr2) {
            int tr = tr0 + tr2;
            #pragma unroll
            for (int g = 0; g < 3; ++g) {
                int tile = g * 13 + tr;
                #pragma unroll
                for (int kt = 0; kt < 7; ++kt)
                    Bf[(tr2*3+g)*7+kt] =
                        *(const half8*)(whB + (size_t)(((kt*39 + tile)*4 + quad)*16 + n16)*8);
            }
        }
        float bh0 = (u0 < H_) ? bhn[u0] : 0.f;
        float bh1 = (ntr > 1 && u1 < H_) ? bhn[u1] : 0.f;

        for (int i = tid; i < 16 * HSTR_; i += 512) hA[i] = (_Float16)0.f;
        __syncthreads();
        if (!first) {
            for (int i = tid; i < 16 * H_; i += 512) {
                int m = i / H_, uu = i - m * H_;
                hA[m * HSTR_ + uu] = hstate[(b0 + m) * H_ + uu];
            }
        }
        __syncthreads();
        float ho[8];
        #pragma unroll
        for (int r = 0; r < 4; ++r) {
            ho[r]     = (float)hA[(quad*4+r)*HSTR_ + u0];
            ho[4 + r] = (ntr > 1) ? (float)hA[(quad*4+r)*HSTR_ + u1] : 0.f;
        }
        const int bg = bid * 4 + quad;
        const float* gB = giBuf + (size_t)bg * TC * NP_ * 4;
        _Float16*    hB = hsBuf + (size_t)bg * TC * GP_ * 4;

        // preload t=0: C = gi_r / gi_z; C_n = bhn; gvn = gi_n (arch)
        f32x4 acc0 = *(const f32x4*)(gB + (size_t)u0 * 4);
        f32x4 acc1 = *(const f32x4*)(gB + (size_t)(GP_ + u0) * 4);
        f32x4 gn0  = *(const f32x4*)(gB + (size_t)(2*GP_ + u0) * 4);
        f32x4 acc2 = (f32x4){bh0, bh0, bh0, bh0};
        f32x4 acc3 = (f32x4){0,0,0,0}, acc4 = acc3, gn1 = acc3;
        f32x4 acc5 = (f32x4){bh1, bh1, bh1, bh1};
        if (ntr > 1) {
            acc3 = *(const f32x4*)(gB + (size_t)u1 * 4);
            acc4 = *(const f32x4*)(gB + (size_t)(GP_ + u1) * 4);
            gn1  = *(const f32x4*)(gB + (size_t)(2*GP_ + u1) * 4);
        }

        for (int t = 0; t < TC; ++t) {
            const _Float16* ha = hA + n16 * HSTR_ + quad * 8;
            #pragma unroll
            for (int kt = 0; kt < 7; ++kt) {
                half8 a = *(const half8*)(ha + kt * 32);
                acc0 = __builtin_amdgcn_mfma_f32_16x16x32_f16(a, Bf[kt],      acc0, 0, 0, 0);
                acc1 = __builtin_amdgcn_mfma_f32_16x16x32_f16(a, Bf[7 + kt],  acc1, 0, 0, 0);
                acc2 = __builtin_amdgcn_mfma_f32_16x16x32_f16(a, Bf[14 + kt], acc2, 0, 0, 0);
                if (ntr > 1) {
                    acc3 = __builtin_amdgcn_mfma_f32_16x16x32_f16(a, Bf[21 + kt], acc3, 0, 0, 0);
                    acc4 = __builtin_amdgcn_mfma_f32_16x16x32_f16(a, Bf[28 + kt], acc4, 0, 0, 0);
                    acc5 = __builtin_amdgcn_mfma_f32_16x16x32_f16(a, Bf[35 + kt], acc5, 0, 0, 0);
                }
            }
            __syncthreads();   // all hA reads done before rewrite
            int tn = (t + 1 < TC) ? t + 1 : t;
            const float* gRow = gB + (size_t)tn * NP_ * 4;

            half4 hv0;
            #pragma unroll
            for (int r = 0; r < 4; ++r) {
                float rr = sig_(acc0[r]);
                float zz = sig_(acc1[r]);
                float nn = tanh_(gn0[r] + rr * acc2[r]);   // acc2 = hh_n + bhn
                float hv = ho[r]; hv = nn + zz * (hv - nn);
                ho[r] = hv; hv0[r] = (_Float16)hv;
                hA[(quad*4+r)*HSTR_ + u0] = hv0[r];
            }
            *(half4*)(hB + ((size_t)t * GP_ + u0) * 4) = hv0;
            acc0 = *(const f32x4*)(gRow + (size_t)u0 * 4);
            acc1 = *(const f32x4*)(gRow + (size_t)(GP_ + u0) * 4);
            gn0  = *(const f32x4*)(gRow + (size_t)(2*GP_ + u0) * 4);
            acc2 = (f32x4){bh0, bh0, bh0, bh0};
            if (ntr > 1) {
                half4 hv1;
                #pragma unroll
                for (int r = 0; r < 4; ++r) {
                    float rr = sig_(acc3[r]);
                    float zz = sig_(acc4[r]);
                    float nn = tanh_(gn1[r] + rr * acc5[r]);
                    float hv = ho[4 + r]; hv = nn + zz * (hv - nn);
                    ho[4 + r] = hv; hv1[r] = (_Float16)hv;
                    hA[(quad*4+r)*HSTR_ + u1] = hv1[r];
                }
                *(half4*)(hB + ((size_t)t * GP_ + u1) * 4) = hv1;
                acc3 = *(const f32x4*)(gRow + (size_t)u1 * 4);
                acc4 = *(const f32x4*)(gRow + (size_t)(GP_ + u1) * 4);
                gn1  = *(const f32x4*)(gRow + (size_t)(2*GP_ + u1) * 4);
                acc5 = (f32x4){bh1, bh1, bh1, bh1};
            }
            __syncthreads();   // hA writes visible before next step's reads
        }
        #pragma unroll
        for (int tr2 = 0; tr2 < 2; ++tr2) {
            if (tr2 < ntr) {
                int ub = tr2 ? u1 : u0;
                if (ub < H_)
                    #pragma unroll
                    for (int r = 0; r < 4; ++r)
                        hstate[(size_t)(b0 + quad*4 + r) * H_ + ub] = (_Float16)ho[tr2*4+r];
            }
        }
    } else if (bid < scanN + giN) {
        // ============ gi = x @ Wi + bi, swizzled [bgrp][t][col][4b] ============
        float* giBuf = (giC & 1) ? gi1 : gi0;
        float* xT = (float*)smem;                     // [100][36]
        int gib = bid - scanN;
        int tpb = TC >> 3;                            // 8-timestep windows per bgrp
        int bg = gib / tpb, tw = gib - bg * tpb;
        int tL0 = tw * 8;
        for (int i = tid; i < 32 * F_; i += 512) {
            int ridx = i / F_, f = i - ridx * F_;
            int rb = ridx >> 3, rt = ridx & 7;
            xT[f * 36 + ridx] =
                x[((size_t)(bg*4 + rb) * T_ + (size_t)giC * TC + tL0 + rt) * F_ + f];
        }
        __syncthreads();
        for (int pass = 0; pass < 2; ++pass) {
            int c = pass * 512 + tid;
            if (c < NP_) {
                int g = c / GP_, u = c - g * GP_;
                bool valid = (u < H_);
                int wcol = valid ? (g * H_ + u) : 0;
                float acc[32];                         // acc[rb*8+rt]
                #pragma unroll
                for (int r = 0; r < 32; ++r) acc[r] = 0.f;
                for (int f = 0; f < F_; ++f) {
                    float wv = Wi[f * G_ + wcol];
                    const f32x4* xf = (const f32x4*)&xT[f * 36];
                    #pragma unroll
                    for (int q = 0; q < 8; ++q) {
                        f32x4 v = xf[q];
                        acc[4*q+0] = fmaf(v[0], wv, acc[4*q+0]);
                        acc[4*q+1] = fmaf(v[1], wv, acc[4*q+1]);
                        acc[4*q+2] = fmaf(v[2], wv, acc[4*q+2]);
                        acc[4*q+3] = fmaf(v[3], wv, acc[4*q+3]);
                    }
                }
                float bv = valid ? bi[g * H_ + u] : 0.f;
                #pragma unroll
                for (int rt = 0; rt < 8; ++rt) {
                    f32x4 v;
                    v[0] = valid ? acc[rt]      + bv : 0.f;
                    v[1] = valid ? acc[8 + rt]  + bv : 0.f;
                    v[2] = valid ? acc[16 + rt] + bv : 0.f;
                    v[3] = valid ? acc[24 + rt] + bv : 0.f;
                    *(f32x4*)(giBuf + (((size_t)bg * TC + tL0 + rt) * NP_ + c) * 4) = v;
                }
            }
        }
    } else {
        // ============ outproj: out = hs @ Wo + bo ============
        const _Float16* hsBuf = (outC & 1) ? hs1 : hs0;
        float* Wos = (float*)smem;
        if (tid < H_) Wos[tid] = Wo[tid];
        __syncthreads();
        int i = (bid - scanN - giN) * 512 + tid;      // over 16*TC*4
        int bl = i & 3, rest = i >> 2;
        int t = rest % TC, bg = rest / TC;
        if (bg < 16) {
            const _Float16* hh = hsBuf + ((size_t)bg * TC + t) * GP_ * 4 + bl;
            float acc = 0.f;
            #pragma unroll 8
            for (int u = 0; u < H_; ++u)
                acc = fmaf((float)hh[u * 4], Wos[u], acc);
            int b = bg * 4 + bl;
            out[(size_t)b * T_ + (size_t)outC * TC + t] = acc + bo[0];
        }
    }
}

extern "C" void kernel_launch(void* const* d_in, const int* in_sizes, int n_in,
                              void* d_out, int out_size, void* d_ws, size_t ws_size,
                              hipStream_t stream) {
    const float* x   = (const float*)d_in[0];
    const float* Wi  = (const float*)d_in[1];
    const float* bi  = (const float*)d_in[2];
    const float* Wh  = (const float*)d_in[3];
    const float* bhn = (const float*)d_in[4];
    const float* Wo  = (const float*)d_in[5];
    const float* bo  = (const float*)d_in[6];
    float* out = (float*)d_out;

    const size_t fixed = (size_t)NWHB_ * 2 + (size_t)B_ * H_ * 2 + 1024;
    int TC = 512;   // keep gi buffers LLC-resident
    while (TC > 64) {
        size_t need = 2 * ((size_t)16 * TC * NP_ * 4 * 4)
                    + 2 * ((size_t)16 * TC * GP_ * 4 * 2) + fixed;
        if (need <= ws_size) break;
        TC >>= 1;
    }
    char* pp = (char*)d_ws;
    float*    gi0 = (float*)pp;     pp += (size_t)16 * TC * NP_ * 4 * 4;
    float*    gi1 = (float*)pp;     pp += (size_t)16 * TC * NP_ * 4 * 4;
    _Float16* hs0 = (_Float16*)pp;  pp += (size_t)16 * TC * GP_ * 4 * 2;
    _Float16* hs1 = (_Float16*)pp;  pp += (size_t)16 * TC * GP_ * 4 * 2;
    _Float16* whB = (_Float16*)pp;  pp += (size_t)NWHB_ * 2;
    _Float16* hstate = (_Float16*)pp;

    const int nch = T_ / TC;
    const int giN = 16 * (TC >> 3);          // bgrp x 8-step windows
    const int outN = B_ * TC / 512;

    prep_whB<<<dim3((NWHB_ + 255) / 256), dim3(256), 0, stream>>>(Wh, whB);
    // prologue: gi chunk 0
    work_kernel<<<dim3(giN), dim3(512), 0, stream>>>(0, giN, 0,
        x, Wi, bi, whB, bhn, Wo, bo, gi0, gi1, hs0, hs1, hstate, out,
        TC, 0, 0, 0);
    for (int c = 0; c < nch; ++c) {
        int gC = (c + 1 < nch) ? c + 1 : -1;
        int oC = (c > 0) ? c - 1 : -1;
        int gn = (gC >= 0) ? giN : 0, on = (oC >= 0) ? outN : 0;
        work_kernel<<<dim3(4 + gn + on), dim3(512), 0, stream>>>(4, gn, on,
            x, Wi, bi, whB, bhn, Wo, bo, gi0, gi1, hs0, hs1, hstate, out,
            TC, c, gC, oC);
    }
    // epilogue: outproj of last chunk
    work_kernel<<<dim3(outN), dim3(512), 0, stream>>>(0, 0, outN,
        x, Wi, bi, whB, bhn, Wo, bo, gi0, gi1, hs0, hs1, hstate, out,
        TC, 0, 0, nch - 1);
}

// Round 6
// 11414.910 us; speedup vs baseline: 3.6858x; 3.2890x over previous
//
#include <hip/hip_runtime.h>
#include <cstdint>

#define B_    64
#define T_    4096
#define F_    100
#define H_    200
#define G_    600
#define GP_   208           // padded gate width (13 tiles of 16)
#define NP_   624           // 3 * GP_
#define HSTR_ 232           // hA row stride in halves
#define NWHB_ (7*39*4*16*8) // whB: [kt][tile][quad][n][j]

typedef _Float16 half8 __attribute__((ext_vector_type(8)));
typedef _Float16 half4 __attribute__((ext_vector_type(4)));
typedef float    f32x4 __attribute__((ext_vector_type(4)));

__device__ __forceinline__ float sig_(float x){ return 1.f/(1.f+__expf(-x)); }
__device__ __forceinline__ float tanh_(float x){ float e=__expf(-2.f*x); return (1.f-e)/(1.f+e); }

// ---- pack Wh [200][600] f32 -> B-fragment layout f16 (validated R4/R5) ----
__global__ void prep_whB(const float* __restrict__ Wh, _Float16* __restrict__ whB) {
    int i = blockIdx.x * 256 + threadIdx.x;
    if (i >= NWHB_) return;
    int j = i & 7, n = (i >> 3) & 15, q = (i >> 7) & 3, rest = i >> 9;
    int tile = rest % 39, kt = rest / 39;
    int k = kt * 32 + q * 8 + j;
    int g = tile / 13, u = (tile % 13) * 16 + n;
    float v = 0.f;
    if (k < H_ && u < H_) v = Wh[k * G_ + g * H_ + u];
    whB[i] = (_Float16)v;
}

// gi layout: [bgrp(16)][t(TC)][col(NP_)][4 batches] f32
// hs layout: [bgrp(16)][t(TC)][u(GP_)][4 batches] f16
__global__ __launch_bounds__(512, 2)
void work_kernel(int scanN, int giN, int outN,
                 const float* __restrict__ x, const float* __restrict__ Wi,
                 const float* __restrict__ bi, const _Float16* __restrict__ whB,
                 const float* __restrict__ bhn, const float* __restrict__ Wo,
                 const float* __restrict__ bo,
                 float* gi0, float* gi1, _Float16* hs0, _Float16* hs1,
                 _Float16* hstate, float* __restrict__ out,
                 int TC, int scanC, int giC, int outC)
{
    __shared__ __align__(16) char smem[7424];
    const int bid = blockIdx.x, tid = threadIdx.x;

    if (bid < scanN) {
        // ============ GRU scan: 16 batches/block, MFMA, static triple unroll ============
        _Float16* hA = (_Float16*)smem;               // [16][HSTR_] f16
        const float* giBuf = (scanC & 1) ? gi1 : gi0;
        _Float16*    hsBuf = (scanC & 1) ? hs1 : hs0;
        const int first = (scanC == 0);
        const int b0 = bid * 16;
        const int w = tid >> 6, l = tid & 63, quad = l >> 4, n16 = l & 15;
        const int tr0 = 2 * w, tr1 = 2 * w + 1;       // 16 triple slots; >=13 are dummies
        const bool v0 = (tr0 < 13), v1 = (tr1 < 13);  // wave-uniform
        const int u0 = tr0 * 16 + n16, u1 = tr1 * 16 + n16;
        const int cu0 = v0 ? u0 : 0, cu1 = v1 ? u1 : 0;   // clamped cols for loads

        half8 Bf[42];                                  // statically indexed ONLY
        #pragma unroll
        for (int i = 0; i < 42; ++i)
            #pragma unroll
            for (int j = 0; j < 8; ++j) Bf[i][j] = (_Float16)0.f;
        if (v0) {
            #pragma unroll
            for (int g = 0; g < 3; ++g) {
                int tile = g * 13 + tr0;
                #pragma unroll
                for (int kt = 0; kt < 7; ++kt)
                    Bf[g * 7 + kt] =
                        *(const half8*)(whB + (size_t)(((kt*39 + tile)*4 + quad)*16 + n16)*8);
            }
        }
        if (v1) {
            #pragma unroll
            for (int g = 0; g < 3; ++g) {
                int tile = g * 13 + tr1;
                #pragma unroll
                for (int kt = 0; kt < 7; ++kt)
                    Bf[21 + g * 7 + kt] =
                        *(const half8*)(whB + (size_t)(((kt*39 + tile)*4 + quad)*16 + n16)*8);
            }
        }
        float bh0 = (v0 && u0 < H_) ? bhn[u0] : 0.f;
        float bh1 = (v1 && u1 < H_) ? bhn[u1] : 0.f;

        for (int i = tid; i < 16 * HSTR_; i += 512) hA[i] = (_Float16)0.f;
        __syncthreads();
        if (!first) {
            for (int i = tid; i < 16 * H_; i += 512) {
                int m = i / H_, uu = i - m * H_;
                hA[m * HSTR_ + uu] = hstate[(b0 + m) * H_ + uu];
            }
        }
        __syncthreads();
        float ho0[4], ho1[4];
        #pragma unroll
        for (int r = 0; r < 4; ++r) {
            ho0[r] = v0 ? (float)hA[(quad*4+r)*HSTR_ + u0] : 0.f;
            ho1[r] = v1 ? (float)hA[(quad*4+r)*HSTR_ + u1] : 0.f;
        }
        const int bg = bid * 4 + quad;
        const float* gB = giBuf + (size_t)bg * TC * (NP_ * 4);
        _Float16*    hB = hsBuf + (size_t)bg * TC * (GP_ * 4);

        // t=0 preload: C_r/C_z = gi; C_n = bhn (MFMA adds hh_n); gn = gi_n (arch)
        f32x4 acc0 = *(const f32x4*)(gB + (size_t)cu0 * 4);
        f32x4 acc1 = *(const f32x4*)(gB + (size_t)(GP_ + cu0) * 4);
        f32x4 gn0  = *(const f32x4*)(gB + (size_t)(2*GP_ + cu0) * 4);
        f32x4 acc2 = (f32x4){bh0, bh0, bh0, bh0};
        f32x4 acc3 = *(const f32x4*)(gB + (size_t)cu1 * 4);
        f32x4 acc4 = *(const f32x4*)(gB + (size_t)(GP_ + cu1) * 4);
        f32x4 gn1  = *(const f32x4*)(gB + (size_t)(2*GP_ + cu1) * 4);
        f32x4 acc5 = (f32x4){bh1, bh1, bh1, bh1};

        for (int t = 0; t < TC; ++t) {
            // prefetch t+1 gi now; consumed at rotation after gates (hidden by MFMA)
            int tn = (t + 1 < TC) ? t + 1 : t;
            const float* gN = gB + (size_t)tn * (NP_ * 4);
            f32x4 p0r = *(const f32x4*)(gN + (size_t)cu0 * 4);
            f32x4 p0z = *(const f32x4*)(gN + (size_t)(GP_ + cu0) * 4);
            f32x4 p0n = *(const f32x4*)(gN + (size_t)(2*GP_ + cu0) * 4);
            f32x4 p1r = *(const f32x4*)(gN + (size_t)cu1 * 4);
            f32x4 p1z = *(const f32x4*)(gN + (size_t)(GP_ + cu1) * 4);
            f32x4 p1n = *(const f32x4*)(gN + (size_t)(2*GP_ + cu1) * 4);

            #pragma unroll
            for (int kt = 0; kt < 7; ++kt) {
                half8 a = *(const half8*)(hA + n16 * HSTR_ + kt * 32 + quad * 8);
                acc0 = __builtin_amdgcn_mfma_f32_16x16x32_f16(a, Bf[kt],      acc0, 0, 0, 0);
                acc1 = __builtin_amdgcn_mfma_f32_16x16x32_f16(a, Bf[7 + kt],  acc1, 0, 0, 0);
                acc2 = __builtin_amdgcn_mfma_f32_16x16x32_f16(a, Bf[14 + kt], acc2, 0, 0, 0);
                acc3 = __builtin_amdgcn_mfma_f32_16x16x32_f16(a, Bf[21 + kt], acc3, 0, 0, 0);
                acc4 = __builtin_amdgcn_mfma_f32_16x16x32_f16(a, Bf[28 + kt], acc4, 0, 0, 0);
                acc5 = __builtin_amdgcn_mfma_f32_16x16x32_f16(a, Bf[35 + kt], acc5, 0, 0, 0);
            }
            __syncthreads();   // all hA reads done before rewrite
            if (v0) {
                half4 hv0;
                #pragma unroll
                for (int r = 0; r < 4; ++r) {
                    float rr = sig_(acc0[r]);
                    float zz = sig_(acc1[r]);
                    float nn = tanh_(gn0[r] + rr * acc2[r]);   // acc2 = hh_n + bhn
                    float hv = ho0[r]; hv = nn + zz * (hv - nn);
                    ho0[r] = hv; hv0[r] = (_Float16)hv;
                    hA[(quad*4+r)*HSTR_ + u0] = hv0[r];
                }
                *(half4*)(hB + ((size_t)t * GP_ + u0) * 4) = hv0;
            }
            if (v1) {
                half4 hv1;
                #pragma unroll
                for (int r = 0; r < 4; ++r) {
                    float rr = sig_(acc3[r]);
                    float zz = sig_(acc4[r]);
                    float nn = tanh_(gn1[r] + rr * acc5[r]);
                    float hv = ho1[r]; hv = nn + zz * (hv - nn);
                    ho1[r] = hv; hv1[r] = (_Float16)hv;
                    hA[(quad*4+r)*HSTR_ + u1] = hv1[r];
                }
                *(half4*)(hB + ((size_t)t * GP_ + u1) * 4) = hv1;
            }
            // rotate prefetched gi into C operands (register-only)
            acc0 = p0r; acc1 = p0z; acc2 = (f32x4){bh0, bh0, bh0, bh0}; gn0 = p0n;
            acc3 = p1r; acc4 = p1z; acc5 = (f32x4){bh1, bh1, bh1, bh1}; gn1 = p1n;
            __syncthreads();   // hA writes visible before next step's reads
        }
        if (v0 && u0 < H_)
            #pragma unroll
            for (int r = 0; r < 4; ++r)
                hstate[(size_t)(b0 + quad*4 + r) * H_ + u0] = (_Float16)ho0[r];
        if (v1 && u1 < H_)
            #pragma unroll
            for (int r = 0; r < 4; ++r)
                hstate[(size_t)(b0 + quad*4 + r) * H_ + u1] = (_Float16)ho1[r];
    } else if (bid < scanN + giN) {
        // ============ gi = x @ Wi + bi, light branch: 8 rows (4 batches x 2 t) ============
        float* giBuf = (giC & 1) ? gi1 : gi0;
        float* xT = (float*)smem;                     // [100][8]: idx = rt*4+rb
        int gib = bid - scanN;
        int tpb = TC >> 1;
        int bg = gib / tpb, tw = gib - bg * tpb;
        size_t tbase = (size_t)giC * TC + tw * 2;
        for (int i = tid; i < 8 * F_; i += 512) {
            int f = i >> 3, idx = i & 7, rt = idx >> 2, rb = idx & 3;
            xT[i] = x[((size_t)(bg*4 + rb) * T_ + tbase + rt) * F_ + f];
        }
        __syncthreads();
        #pragma unroll
        for (int pass = 0; pass < 2; ++pass) {
            int c = pass * 512 + tid;
            if (c < NP_) {
                int g = c / GP_, u = c - g * GP_;
                bool valid = (u < H_);
                int wcol = valid ? (g * H_ + u) : 0;
                f32x4 a0 = (f32x4){0,0,0,0}, a1 = (f32x4){0,0,0,0};
                for (int f = 0; f < F_; ++f) {
                    float wv = Wi[f * G_ + wcol];
                    const f32x4* xp = (const f32x4*)(xT + f * 8);
                    a0 += xp[0] * wv;
                    a1 += xp[1] * wv;
                }
                float bv = valid ? bi[wcol] : 0.f;
                f32x4 s0, s1;
                #pragma unroll
                for (int j = 0; j < 4; ++j) {
                    s0[j] = valid ? a0[j] + bv : 0.f;
                    s1[j] = valid ? a1[j] + bv : 0.f;
                }
                size_t base = ((size_t)bg * TC + tw * 2) * (NP_ * 4);
                *(f32x4*)(giBuf + base + (size_t)c * 4) = s0;
                *(f32x4*)(giBuf + base + (size_t)(NP_ * 4) + (size_t)c * 4) = s1;
            }
        }
    } else {
        // ============ outproj: out = hs @ Wo + bo ============
        const _Float16* hsBuf = (outC & 1) ? hs1 : hs0;
        float* Wos = (float*)smem;
        if (tid < H_) Wos[tid] = Wo[tid];
        __syncthreads();
        int i = (bid - scanN - giN) * 512 + tid;      // over 16*TC*4
        int bl = i & 3, rest = i >> 2;
        int t = rest % TC, bg = rest / TC;
        if (bg < 16) {
            const _Float16* hh = hsBuf + ((size_t)bg * TC + t) * (GP_ * 4) + bl;
            float acc = 0.f;
            #pragma unroll 8
            for (int u = 0; u < H_; ++u)
                acc = fmaf((float)hh[u * 4], Wos[u], acc);
            int b = bg * 4 + bl;
            out[(size_t)b * T_ + (size_t)outC * TC + t] = acc + bo[0];
        }
    }
}

extern "C" void kernel_launch(void* const* d_in, const int* in_sizes, int n_in,
                              void* d_out, int out_size, void* d_ws, size_t ws_size,
                              hipStream_t stream) {
    const float* x   = (const float*)d_in[0];
    const float* Wi  = (const float*)d_in[1];
    const float* bi  = (const float*)d_in[2];
    const float* Wh  = (const float*)d_in[3];
    const float* bhn = (const float*)d_in[4];
    const float* Wo  = (const float*)d_in[5];
    const float* bo  = (const float*)d_in[6];
    float* out = (float*)d_out;

    const size_t fixed = (size_t)NWHB_ * 2 + (size_t)B_ * H_ * 2 + 1024;
    int TC = 512;
    while (TC > 64) {
        size_t need = 2 * ((size_t)16 * TC * NP_ * 4 * sizeof(float))
                    + 2 * ((size_t)16 * TC * GP_ * 4 * sizeof(_Float16)) + fixed;
        if (need <= ws_size) break;
        TC >>= 1;
    }
    char* pp = (char*)d_ws;
    float*    gi0 = (float*)pp;     pp += (size_t)16 * TC * NP_ * 4 * sizeof(float);
    float*    gi1 = (float*)pp;     pp += (size_t)16 * TC * NP_ * 4 * sizeof(float);
    _Float16* hs0 = (_Float16*)pp;  pp += (size_t)16 * TC * GP_ * 4 * sizeof(_Float16);
    _Float16* hs1 = (_Float16*)pp;  pp += (size_t)16 * TC * GP_ * 4 * sizeof(_Float16);
    _Float16* whB = (_Float16*)pp;  pp += (size_t)NWHB_ * 2;
    _Float16* hstate = (_Float16*)pp;

    const int nch = T_ / TC;
    const int giN = 16 * (TC >> 1);          // bgrp x 2-step windows
    const int outN = B_ * TC / 512;

    prep_whB<<<dim3((NWHB_ + 255) / 256), dim3(256), 0, stream>>>(Wh, whB);
    // prologue: gi chunk 0
    work_kernel<<<dim3(giN), dim3(512), 0, stream>>>(0, giN, 0,
        x, Wi, bi, whB, bhn, Wo, bo, gi0, gi1, hs0, hs1, hstate, out,
        TC, 0, 0, 0);
    for (int c = 0; c < nch; ++c) {
        int gC = (c + 1 < nch) ? c + 1 : -1;
        int oC = (c > 0) ? c - 1 : -1;
        int gn = (gC >= 0) ? giN : 0, on = (oC >= 0) ? outN : 0;
        work_kernel<<<dim3(4 + gn + on), dim3(512), 0, stream>>>(4, gn, on,
            x, Wi, bi, whB, bhn, Wo, bo, gi0, gi1, hs0, hs1, hstate, out,
            TC, c, gC, oC);
    }
    // epilogue: outproj of last chunk
    work_kernel<<<dim3(outN), dim3(512), 0, stream>>>(0, 0, outN,
        x, Wi, bi, whB, bhn, Wo, bo, gi0, gi1, hs0, hs1, hstate, out,
        TC, 0, 0, nch - 1);
}

// Round 7
// 6528.395 us; speedup vs baseline: 6.4446x; 1.7485x over previous
//
#include <hip/hip_runtime.h>
#include <cstdint>

#define B_    64
#define T_    4096
#define F_    100
#define H_    200
#define G_    600
#define GP_   208           // padded gate width (13 tiles of 16)
#define NP_   624           // 3 * GP_
#define HSTR_ 232           // hA row stride in halves
#define NWHB_ (7*39*4*16*8) // whB: [kt][tile][quad][n][j]
#define L2E_  1.4426950408889634f

typedef _Float16 half8 __attribute__((ext_vector_type(8)));
typedef _Float16 half4 __attribute__((ext_vector_type(4)));
typedef float    f32x4 __attribute__((ext_vector_type(4)));

#if __has_builtin(__builtin_amdgcn_exp2f) && __has_builtin(__builtin_amdgcn_rcpf)
__device__ __forceinline__ float sig_(float x){
    return __builtin_amdgcn_rcpf(1.f + __builtin_amdgcn_exp2f(-L2E_ * x));
}
__device__ __forceinline__ float tanh_(float x){
    return 1.f - 2.f * __builtin_amdgcn_rcpf(1.f + __builtin_amdgcn_exp2f(2.f * L2E_ * x));
}
#else
__device__ __forceinline__ float sig_(float x){ return 1.f/(1.f+__expf(-x)); }
__device__ __forceinline__ float tanh_(float x){ float e=__expf(-2.f*x); return (1.f-e)/(1.f+e); }
#endif

__device__ __forceinline__ f32x4 cvt4_(half4 v){
    f32x4 r; r[0]=(float)v[0]; r[1]=(float)v[1]; r[2]=(float)v[2]; r[3]=(float)v[3];
    return r;
}

// ---- pack Wh [200][600] f32 -> B-fragment layout f16 (validated R4-R6) ----
__global__ void prep_whB(const float* __restrict__ Wh, _Float16* __restrict__ whB) {
    int i = blockIdx.x * 256 + threadIdx.x;
    if (i >= NWHB_) return;
    int j = i & 7, n = (i >> 3) & 15, q = (i >> 7) & 3, rest = i >> 9;
    int tile = rest % 39, kt = rest / 39;
    int k = kt * 32 + q * 8 + j;
    int g = tile / 13, u = (tile % 13) * 16 + n;
    float v = 0.f;
    if (k < H_ && u < H_) v = Wh[k * G_ + g * H_ + u];
    whB[i] = (_Float16)v;
}

// gi layout: [bgrp(16)][t(TC)][col(NP_)][4 batches] f16
// hs layout: [bgrp(16)][t(TC)][u(GP_)][4 batches] f16
__global__ __launch_bounds__(512, 2)
void work_kernel(int scanN, int giN, int outN,
                 const float* __restrict__ x, const float* __restrict__ Wi,
                 const float* __restrict__ bi, const _Float16* __restrict__ whB,
                 const float* __restrict__ bhn, const float* __restrict__ Wo,
                 const float* __restrict__ bo,
                 _Float16* gi0, _Float16* gi1, _Float16* hs0, _Float16* hs1,
                 _Float16* hstate, float* __restrict__ out,
                 int TC, int scanC, int giC, int outC)
{
    __shared__ __align__(16) char smem[14848];
    const int bid = blockIdx.x, tid = threadIdx.x;

    if (bid < scanN) {
        // ============ GRU scan: 16 batches/block, MFMA, 1 barrier/step ============
        _Float16* hA0 = (_Float16*)smem;              // [16][HSTR_] double-buffered
        _Float16* hA1 = hA0 + 16 * HSTR_;
        const _Float16* giBuf = (scanC & 1) ? gi1 : gi0;
        _Float16*       hsBuf = (scanC & 1) ? hs1 : hs0;
        const int first = (scanC == 0);
        const int b0 = bid * 16;
        const int w = tid >> 6, l = tid & 63, quad = l >> 4, n16 = l & 15;
        const int tr0 = 2 * w, tr1 = 2 * w + 1;       // 16 slots; >=13 dummy
        const bool v0 = (tr0 < 13), v1 = (tr1 < 13);  // wave-uniform
        const int u0 = tr0 * 16 + n16, u1 = tr1 * 16 + n16;
        const int cu0 = v0 ? u0 : 0, cu1 = v1 ? u1 : 0;

        half8 Bf[42];                                  // statically indexed only
        #pragma unroll
        for (int i = 0; i < 42; ++i)
            #pragma unroll
            for (int j = 0; j < 8; ++j) Bf[i][j] = (_Float16)0.f;
        if (v0) {
            #pragma unroll
            for (int g = 0; g < 3; ++g) {
                int tile = g * 13 + tr0;
                #pragma unroll
                for (int kt = 0; kt < 7; ++kt)
                    Bf[g * 7 + kt] =
                        *(const half8*)(whB + (size_t)(((kt*39 + tile)*4 + quad)*16 + n16)*8);
            }
        }
        if (v1) {
            #pragma unroll
            for (int g = 0; g < 3; ++g) {
                int tile = g * 13 + tr1;
                #pragma unroll
                for (int kt = 0; kt < 7; ++kt)
                    Bf[21 + g * 7 + kt] =
                        *(const half8*)(whB + (size_t)(((kt*39 + tile)*4 + quad)*16 + n16)*8);
            }
        }
        float bh0 = (v0 && u0 < H_) ? bhn[u0] : 0.f;
        float bh1 = (v1 && u1 < H_) ? bhn[u1] : 0.f;

        for (int i = tid; i < 2 * 16 * HSTR_; i += 512) hA0[i] = (_Float16)0.f;
        __syncthreads();
        if (!first) {
            for (int i = tid; i < 16 * H_; i += 512) {
                int m = i / H_, uu = i - m * H_;
                hA0[m * HSTR_ + uu] = hstate[(b0 + m) * H_ + uu];
            }
        }
        __syncthreads();

        const int bg = bid * 4 + quad;
        const _Float16* gB = giBuf + (size_t)bg * TC * (NP_ * 4);
        _Float16* hRow = hsBuf + (size_t)bg * TC * (GP_ * 4);

        // preload t=0: C_r/C_z = gi (f32 cvt); C_n = bhn; gn = gi_n (f16)
        f32x4 acc0 = cvt4_(*(const half4*)(gB + (size_t)cu0 * 4));
        f32x4 acc1 = cvt4_(*(const half4*)(gB + (size_t)(GP_ + cu0) * 4));
        half4 gn0  = *(const half4*)(gB + (size_t)(2*GP_ + cu0) * 4);
        f32x4 acc2 = (f32x4){bh0, bh0, bh0, bh0};
        f32x4 acc3 = cvt4_(*(const half4*)(gB + (size_t)cu1 * 4));
        f32x4 acc4 = cvt4_(*(const half4*)(gB + (size_t)(GP_ + cu1) * 4));
        half4 gn1  = *(const half4*)(gB + (size_t)(2*GP_ + cu1) * 4);
        f32x4 acc5 = (f32x4){bh1, bh1, bh1, bh1};

        const _Float16* gNext = gB + NP_ * 4;   // row t+1 (last iter overruns into
                                                // adjacent ws buffer: allocated, unused)
        _Float16* hRd = hA0; _Float16* hWr = hA1;

        for (int t = 0; t < TC; ++t) {
            // prefetch t+1 gi (f16, 8B/lane coalesced); consumed at rotation
            half4 p0 = *(const half4*)(gNext + (size_t)cu0 * 4);
            half4 p1 = *(const half4*)(gNext + (size_t)(GP_ + cu0) * 4);
            half4 p2 = *(const half4*)(gNext + (size_t)(2*GP_ + cu0) * 4);
            half4 p3 = *(const half4*)(gNext + (size_t)cu1 * 4);
            half4 p4 = *(const half4*)(gNext + (size_t)(GP_ + cu1) * 4);
            half4 p5 = *(const half4*)(gNext + (size_t)(2*GP_ + cu1) * 4);

            #pragma unroll
            for (int kt = 0; kt < 7; ++kt) {
                half8 a = *(const half8*)(hRd + n16 * HSTR_ + kt * 32 + quad * 8);
                acc0 = __builtin_amdgcn_mfma_f32_16x16x32_f16(a, Bf[kt],      acc0, 0, 0, 0);
                acc1 = __builtin_amdgcn_mfma_f32_16x16x32_f16(a, Bf[7 + kt],  acc1, 0, 0, 0);
                acc2 = __builtin_amdgcn_mfma_f32_16x16x32_f16(a, Bf[14 + kt], acc2, 0, 0, 0);
                acc3 = __builtin_amdgcn_mfma_f32_16x16x32_f16(a, Bf[21 + kt], acc3, 0, 0, 0);
                acc4 = __builtin_amdgcn_mfma_f32_16x16x32_f16(a, Bf[28 + kt], acc4, 0, 0, 0);
                acc5 = __builtin_amdgcn_mfma_f32_16x16x32_f16(a, Bf[35 + kt], acc5, 0, 0, 0);
            }
            // gates write the OTHER hA buffer: no WAR with concurrent readers
            if (v0) {
                half4 hv0;
                #pragma unroll
                for (int r = 0; r < 4; ++r) {
                    float rr = sig_(acc0[r]);
                    float zz = sig_(acc1[r]);
                    float nn = tanh_((float)gn0[r] + rr * acc2[r]);   // acc2 = hh_n + bhn
                    float hold = (float)hRd[(quad*4+r)*HSTR_ + u0];
                    float hv = nn + zz * (hold - nn);
                    hv0[r] = (_Float16)hv;
                    hWr[(quad*4+r)*HSTR_ + u0] = hv0[r];
                }
                *(half4*)(hRow + (size_t)u0 * 4) = hv0;
            }
            if (v1) {
                half4 hv1;
                #pragma unroll
                for (int r = 0; r < 4; ++r) {
                    float rr = sig_(acc3[r]);
                    float zz = sig_(acc4[r]);
                    float nn = tanh_((float)gn1[r] + rr * acc5[r]);
                    float hold = (float)hRd[(quad*4+r)*HSTR_ + u1];
                    float hv = nn + zz * (hold - nn);
                    hv1[r] = (_Float16)hv;
                    hWr[(quad*4+r)*HSTR_ + u1] = hv1[r];
                }
                *(half4*)(hRow + (size_t)u1 * 4) = hv1;
            }
            // rotate prefetched gi into C operands (register-only)
            acc0 = cvt4_(p0); acc1 = cvt4_(p1); gn0 = p2;
            acc2 = (f32x4){bh0, bh0, bh0, bh0};
            acc3 = cvt4_(p3); acc4 = cvt4_(p4); gn1 = p5;
            acc5 = (f32x4){bh1, bh1, bh1, bh1};
            __syncthreads();   // hWr writes visible before next step's reads
            _Float16* tmp = hRd; hRd = hWr; hWr = tmp;
            gNext += NP_ * 4; hRow += GP_ * 4;
        }
        // final h lives in hRd (f16)
        if (v0 && u0 < H_)
            #pragma unroll
            for (int r = 0; r < 4; ++r)
                hstate[(size_t)(b0 + quad*4 + r) * H_ + u0] = hRd[(quad*4+r)*HSTR_ + u0];
        if (v1 && u1 < H_)
            #pragma unroll
            for (int r = 0; r < 4; ++r)
                hstate[(size_t)(b0 + quad*4 + r) * H_ + u1] = hRd[(quad*4+r)*HSTR_ + u1];
    } else if (bid < scanN + giN) {
        // ============ gi = x @ Wi + bi -> f16, swizzled [bgrp][t][col][4b] ============
        _Float16* giBuf = (giC & 1) ? gi1 : gi0;
        float* xT = (float*)smem;                     // [100][8]: idx = rt*4+rb
        int gib = bid - scanN;
        int tpb = TC >> 1;
        int bg = gib / tpb, tw = gib - bg * tpb;
        size_t tbase = (size_t)giC * TC + tw * 2;
        for (int i = tid; i < 8 * F_; i += 512) {
            int f = i >> 3, idx = i & 7, rt = idx >> 2, rb = idx & 3;
            xT[i] = x[((size_t)(bg*4 + rb) * T_ + tbase + rt) * F_ + f];
        }
        __syncthreads();
        #pragma unroll
        for (int pass = 0; pass < 2; ++pass) {
            int c = pass * 512 + tid;
            if (c < NP_) {
                int g = c / GP_, u = c - g * GP_;
                bool valid = (u < H_);
                int wcol = valid ? (g * H_ + u) : 0;
                f32x4 a0 = (f32x4){0,0,0,0}, a1 = (f32x4){0,0,0,0};
                for (int f = 0; f < F_; ++f) {
                    float wv = Wi[f * G_ + wcol];
                    const f32x4* xp = (const f32x4*)(xT + f * 8);
                    a0 += xp[0] * wv;
                    a1 += xp[1] * wv;
                }
                float bv = valid ? bi[wcol] : 0.f;
                half4 s0, s1;
                #pragma unroll
                for (int j = 0; j < 4; ++j) {
                    s0[j] = (_Float16)(valid ? a0[j] + bv : 0.f);
                    s1[j] = (_Float16)(valid ? a1[j] + bv : 0.f);
                }
                size_t base = ((size_t)bg * TC + tw * 2) * (NP_ * 4);
                *(half4*)(giBuf + base + (size_t)c * 4) = s0;
                *(half4*)(giBuf + base + (size_t)(NP_ * 4) + (size_t)c * 4) = s1;
            }
        }
    } else {
        // ============ outproj: out = hs @ Wo + bo ============
        const _Float16* hsBuf = (outC & 1) ? hs1 : hs0;
        float* Wos = (float*)smem;
        if (tid < H_) Wos[tid] = Wo[tid];
        __syncthreads();
        int i = (bid - scanN - giN) * 512 + tid;      // over 16*TC*4
        int bl = i & 3, rest = i >> 2;
        int t = rest % TC, bg = rest / TC;
        if (bg < 16) {
            const _Float16* hh = hsBuf + ((size_t)bg * TC + t) * (GP_ * 4) + bl;
            float acc = 0.f;
            #pragma unroll 8
            for (int u = 0; u < H_; ++u)
                acc = fmaf((float)hh[u * 4], Wos[u], acc);
            int b = bg * 4 + bl;
            out[(size_t)b * T_ + (size_t)outC * TC + t] = acc + bo[0];
        }
    }
}

extern "C" void kernel_launch(void* const* d_in, const int* in_sizes, int n_in,
                              void* d_out, int out_size, void* d_ws, size_t ws_size,
                              hipStream_t stream) {
    const float* x   = (const float*)d_in[0];
    const float* Wi  = (const float*)d_in[1];
    const float* bi  = (const float*)d_in[2];
    const float* Wh  = (const float*)d_in[3];
    const float* bhn = (const float*)d_in[4];
    const float* Wo  = (const float*)d_in[5];
    const float* bo  = (const float*)d_in[6];
    float* out = (float*)d_out;

    const size_t fixed = (size_t)NWHB_ * 2 + (size_t)B_ * H_ * 2 + 1024;
    int TC = 512;
    while (TC > 64) {
        size_t need = 2 * ((size_t)16 * TC * NP_ * 4 * sizeof(_Float16))
                    + 2 * ((size_t)16 * TC * GP_ * 4 * sizeof(_Float16)) + fixed;
        if (need <= ws_size) break;
        TC >>= 1;
    }
    char* pp = (char*)d_ws;
    _Float16* gi0 = (_Float16*)pp;  pp += (size_t)16 * TC * NP_ * 4 * sizeof(_Float16);
    _Float16* gi1 = (_Float16*)pp;  pp += (size_t)16 * TC * NP_ * 4 * sizeof(_Float16);
    _Float16* hs0 = (_Float16*)pp;  pp += (size_t)16 * TC * GP_ * 4 * sizeof(_Float16);
    _Float16* hs1 = (_Float16*)pp;  pp += (size_t)16 * TC * GP_ * 4 * sizeof(_Float16);
    _Float16* whB = (_Float16*)pp;  pp += (size_t)NWHB_ * 2;
    _Float16* hstate = (_Float16*)pp;

    const int nch = T_ / TC;
    const int giN = 16 * (TC >> 1);          // bgrp x 2-step windows
    const int outN = B_ * TC / 512;

    prep_whB<<<dim3((NWHB_ + 255) / 256), dim3(256), 0, stream>>>(Wh, whB);
    // prologue: gi chunk 0
    work_kernel<<<dim3(giN), dim3(512), 0, stream>>>(0, giN, 0,
        x, Wi, bi, whB, bhn, Wo, bo, gi0, gi1, hs0, hs1, hstate, out,
        TC, 0, 0, 0);
    for (int c = 0; c < nch; ++c) {
        int gC = (c + 1 < nch) ? c + 1 : -1;
        int oC = (c > 0) ? c - 1 : -1;
        int gn = (gC >= 0) ? giN : 0, on = (oC >= 0) ? outN : 0;
        work_kernel<<<dim3(4 + gn + on), dim3(512), 0, stream>>>(4, gn, on,
            x, Wi, bi, whB, bhn, Wo, bo, gi0, gi1, hs0, hs1, hstate, out,
            TC, c, gC, oC);
    }
    // epilogue: outproj of last chunk
    work_kernel<<<dim3(outN), dim3(512), 0, stream>>>(0, 0, outN,
        x, Wi, bi, whB, bhn, Wo, bo, gi0, gi1, hs0, hs1, hstate, out,
        TC, 0, 0, nch - 1);
}